// Round 3
// baseline (586.490 us; speedup 1.0000x reference)
//
#include <hip/hip_runtime.h>
#include <hip/hip_bf16.h>

// Newsvendor layer: per-row 1-D convex solve (bisection+Newton) + elementwise outputs.
// One block per row. Prefix-sum + moments make each bisection decision O(1).

constexpr int NS   = 1001;   // support size
constexpr int SPAD = 1024;   // padded (multiple of 4*NT/... covers NS+1)
constexpr int NT   = 256;    // threads per block

__global__ __launch_bounds__(NT) void newsvendor_kernel(
    const float* __restrict__ x,     // [B, NS]
    const float* __restrict__ ysup,  // [NS]
    float* __restrict__ out,         // [B + 3*B*NS]  (z, pinball, e, w_error)
    int B)
{
    __shared__ float  sp[SPAD];
    __shared__ float  sy[SPAD];
    __shared__ double scdf[SPAD];    // exclusive prefix sums of p (fp64)
    __shared__ double wred[12];      // per-wave moment partials (A,B1,C)x4
    __shared__ double wtot[4];       // per-wave scan totals
    __shared__ int    wredi[4];      // per-wave kmin
    __shared__ double bc[4];         // broadcast A,B1,C
    __shared__ float  zf_sh;

    const int row  = blockIdx.x;
    const int tid  = threadIdx.x;
    const int lane = tid & 63;
    const int wv   = tid >> 6;
    const float* xr = x + (size_t)row * NS;

    // ---- stage row + support into LDS (pad p with 0, y with sentinel) ----
    for (int i = tid; i < SPAD; i += NT) {
        sp[i] = (i < NS) ? xr[i]   : 0.0f;
        sy[i] = (i < NS) ? ysup[i] : 2.0f;
    }
    __syncthreads();

    // ---- fp64 moments: A=sum p^2, B1=sum p^2 y, C=sum p^2 y^2 ----
    double a = 0.0, b1 = 0.0, c2 = 0.0;
    for (int i = tid; i < NS; i += NT) {
        double p = (double)sp[i], y = (double)sy[i];
        double pp = p * p;
        a += pp; b1 += pp * y; c2 += pp * (y * y);
    }
    for (int off = 32; off > 0; off >>= 1) {
        a  += __shfl_xor(a,  off);
        b1 += __shfl_xor(b1, off);
        c2 += __shfl_xor(c2, off);
    }
    if (lane == 0) { wred[wv*3+0] = a; wred[wv*3+1] = b1; wred[wv*3+2] = c2; }

    // ---- fp64 exclusive prefix scan of p (each thread owns 4 contiguous) ----
    const int base = tid * 4;
    double p0 = sp[base], p1 = sp[base+1], p2 = sp[base+2], p3 = sp[base+3];
    double l0 = 0.0, l1 = p0, l2 = p0+p1, l3 = p0+p1+p2;
    double s  = p0+p1+p2+p3;
    double inc = s;
    for (int d = 1; d < 64; d <<= 1) {
        double t = __shfl_up(inc, (unsigned)d);
        if (lane >= d) inc += t;
    }
    if (lane == 63) wtot[wv] = inc;
    __syncthreads();

    double woff = 0.0;
    for (int w = 0; w < wv; ++w) woff += wtot[w];
    double ebase = woff + (inc - s);      // exclusive base for this thread
    scdf[base]   = ebase + l0;
    scdf[base+1] = ebase + l1;
    scdf[base+2] = ebase + l2;
    scdf[base+3] = ebase + l3;
    if (tid == 0) {
        bc[0] = wred[0]+wred[3]+wred[6]+wred[9];
        bc[1] = wred[1]+wred[4]+wred[7]+wred[10];
        bc[2] = wred[2]+wred[5]+wred[8]+wred[11];
    }
    __syncthreads();

    const double A   = bc[0], B1 = bc[1], C = bc[2];
    const double Pt  = scdf[NS];          // total prob mass
    const double ca  = (double)0.6f;      // fp32(TAU)
    const double cb  = (double)0.4f;      // fp32(1-TAU)
    const double cab = ca + cb;           // step coefficient (fp32-exact model)
    const double GA  = (double)0.1f;      // fp32(GAMMA)
    const double EPSd = (double)1e-12f;

    // ---- parallel pass: G_k = g(y_k) with count(y_k)=k; find first k with G_k>=0 ----
    int kmin = 0x7fffffff;
    for (int k = tid; k < NS; k += NT) {
        double z  = (double)sy[k];
        double s1 = B1 - z * A;
        double q  = C - z * (2.0 * B1 - z * A);
        double nr = sqrt(q + EPSd);
        double g  = cab * scdf[k] - ca * Pt - GA * s1 / nr;
        if (g >= 0.0) kmin = min(kmin, k);
    }
    for (int off = 32; off > 0; off >>= 1)
        kmin = min(kmin, __shfl_xor(kmin, off));
    if (lane == 0) wredi[wv] = kmin;
    __syncthreads();

    // ---- thread 0: resolve crossing, replay fp32 bisection, Newton, clamp ----
    if (tid == 0) {
        int kstar = min(min(wredi[0], wredi[1]), min(wredi[2], wredi[3]));

        // boundary values g(0), g(1) exactly as the reference evaluates them
        double g0 = -ca * Pt - GA * B1 / sqrt(C + EPSd);                 // count=0
        int c1 = (sy[NS-1] < 1.0f) ? NS : NS - 1;                         // #{y_i < 1}
        double s1b = B1 - A;
        double q1  = C - (2.0 * B1 - A);
        double g1 = cab * scdf[c1] - ca * Pt - GA * s1b / sqrt(q1 + EPSd);

        float zf;
        if (g0 >= 0.0)      zf = 0.0f;
        else if (g1 <= 0.0) zf = 1.0f;
        else {
            int kk = kstar;
            float zlF, zrF;
            if (kk >= NS) { kk = NS; zlF = sy[NS-1]; zrF = 1.0f; }
            else {
                zlF = (kk > 0) ? sy[kk-1] : 0.0f;
                zrF = sy[kk];
            }
            double Phat = cab * scdf[kk] - ca * Pt;

            auto Feval = [&](double z, double& gp) -> double {
                double s1 = B1 - z * A;
                double q  = C - z * (2.0 * B1 - z * A);
                double nr = sqrt(q + EPSd);
                gp = GA * (A / nr - (s1 * s1) / (nr * nr * nr));
                return Phat - GA * s1 / nr;
            };

            double dgp;
            double Fl = Feval((double)zlF, dgp);
            bool  jumpc;
            double zeta;
            if (Fl >= 0.0) { jumpc = true; zeta = (double)zlF; }     // crossing at grid jump
            else {
                jumpc = false;                                        // interior smooth root
                double lo = (double)zlF, hi = (double)zrF;
                double z = 0.5 * (lo + hi);
                for (int it = 0; it < 30; ++it) {
                    double gp; double F = Feval(z, gp);
                    if (F < 0.0) lo = z; else hi = z;
                    double zn = z - F / fmax(gp, 1e-300);
                    if (!(zn > lo && zn < hi)) zn = 0.5 * (lo + hi);  // safeguarded
                    z = zn;
                }
                zeta = z;
            }

            // exact fp32 replay of the reference's 60 bisection iterations
            float flo = 0.0f, fhi = 1.0f;
            for (int it = 0; it < 60; ++it) {
                float mid = 0.5f * (flo + fhi);
                bool dec = jumpc ? (mid <= zlF) : ((double)mid < zeta); // == [g(mid) < 0]
                if (dec) flo = mid; else fhi = mid;
            }
            float z0 = 0.5f * (flo + fhi);

            // count(z0) = #{ y_i < z0 }  (z0 lies within ~ulp of zeta, inside the cell)
            int cnt = (kk - 1) + ((zlF < z0) ? 1 : 0) + ((zrF < z0) ? 1 : 0);
            if (cnt < 0) cnt = 0;

            // Newton step at z0 (reference: z = z0 - g/max(gp,1e-8)), then clip
            double z0d = (double)z0;
            double s1 = B1 - z0d * A;
            double q  = C - z0d * (2.0 * B1 - z0d * A);
            double nr = sqrt(q + EPSd);
            double g  = cab * scdf[cnt] - ca * Pt - GA * s1 / nr;
            double gp = GA * (A / nr - (s1 * s1) / (nr * nr * nr));
            double zn = z0d - g / fmax(gp, (double)1e-8f);
            zn = fmin(fmax(zn, 0.0), 1.0);
            zf = (float)zn;
        }
        zf_sh = zf;
    }
    __syncthreads();

    // ---- outputs: z, pinball, e, w_error (fp32, coalesced rows) ----
    const float zf = zf_sh;
    const size_t Bz = (size_t)B;
    const size_t rb = (size_t)row * NS;
    float* outPin = out + Bz + rb;
    float* outE   = out + Bz + Bz * NS + rb;
    float* outW   = out + Bz + 2 * Bz * NS + rb;
    if (tid == 0) out[row] = zf;
    for (int i = tid; i < NS; i += NT) {
        float e  = sy[i] - zf;
        float pb = fmaxf(0.6f * e, -0.4f * e);   // fp32(TAU)=0.6f, fp32(TAU-1)=-0.4f
        outPin[i] = pb;
        outE[i]   = e;
        outW[i]   = sp[i] * e;
    }
}

extern "C" void kernel_launch(void* const* d_in, const int* in_sizes, int n_in,
                              void* d_out, int out_size, void* d_ws, size_t ws_size,
                              hipStream_t stream)
{
    const float* x = (const float*)d_in[0];
    const float* y = (const float*)d_in[1];
    float* out = (float*)d_out;
    const int Ssz = in_sizes[1];          // 1001
    const int B   = in_sizes[0] / Ssz;    // 32768
    newsvendor_kernel<<<B, NT, 0, stream>>>(x, y, out, B);
}

// Round 4
// 551.371 us; speedup vs baseline: 1.0637x; 1.0637x over previous
//
#include <hip/hip_runtime.h>
#include <hip/hip_bf16.h>

// Newsvendor layer: per-row 1-D convex solve + elementwise outputs.
// One block per row. Prefix-sum + moments give O(1) decisions; interior
// root has a CLOSED FORM (no Newton iterations): with E = C*A - B1^2 + A*eps
// (z-independent), c = Phat/(GA*sqrt(A)), root u = c*sqrt(E/(1-c^2)),
// zeta = (B1-u)/A. Parallel sign pass uses squared compares (no div/sqrt).

constexpr int NS   = 1001;   // support size
constexpr int SPAD = 1024;   // padded
constexpr int NT   = 256;    // threads per block

__global__ __launch_bounds__(NT) void newsvendor_kernel(
    const float* __restrict__ x,     // [B, NS]
    const float* __restrict__ ysup,  // [NS]
    float* __restrict__ out,         // [B + 3*B*NS]  (z, pinball, e, w_error)
    int B)
{
    __shared__ float  sp[SPAD];
    __shared__ float  sy[SPAD];
    __shared__ double scdf[SPAD];    // exclusive prefix sums of p (fp64)
    __shared__ double wred[12];      // per-wave moment partials (A,B1,C)x4
    __shared__ double wtot[4];       // per-wave scan totals
    __shared__ int    wredi[4];      // per-wave kmin
    __shared__ double bc[4];         // broadcast A,B1,C
    __shared__ float  zf_sh;

    const int row  = blockIdx.x;
    const int tid  = threadIdx.x;
    const int lane = tid & 63;
    const int wv   = tid >> 6;
    const float* xr = x + (size_t)row * NS;

    // ---- stage row + support into LDS (pad p with 0, y with sentinel) ----
    for (int i = tid; i < SPAD; i += NT) {
        sp[i] = (i < NS) ? xr[i]   : 0.0f;
        sy[i] = (i < NS) ? ysup[i] : 2.0f;
    }
    __syncthreads();

    // ---- fp64 moments: A=sum p^2, B1=sum p^2 y, C=sum p^2 y^2 ----
    double a = 0.0, b1 = 0.0, c2 = 0.0;
    for (int i = tid; i < NS; i += NT) {
        double p = (double)sp[i], y = (double)sy[i];
        double pp = p * p;
        a += pp; b1 += pp * y; c2 += pp * (y * y);
    }
    for (int off = 32; off > 0; off >>= 1) {
        a  += __shfl_xor(a,  off);
        b1 += __shfl_xor(b1, off);
        c2 += __shfl_xor(c2, off);
    }
    if (lane == 0) { wred[wv*3+0] = a; wred[wv*3+1] = b1; wred[wv*3+2] = c2; }

    // ---- fp64 exclusive prefix scan of p (each thread owns 4 contiguous) ----
    const int base = tid * 4;
    double p0 = sp[base], p1 = sp[base+1], p2 = sp[base+2], p3 = sp[base+3];
    double l0 = 0.0, l1 = p0, l2 = p0+p1, l3 = p0+p1+p2;
    double s  = p0+p1+p2+p3;
    double inc = s;
    for (int d = 1; d < 64; d <<= 1) {
        double t = __shfl_up(inc, (unsigned)d);
        if (lane >= d) inc += t;
    }
    if (lane == 63) wtot[wv] = inc;
    __syncthreads();

    double woff = 0.0;
    for (int w = 0; w < wv; ++w) woff += wtot[w];
    double ebase = woff + (inc - s);      // exclusive base for this thread
    scdf[base]   = ebase + l0;
    scdf[base+1] = ebase + l1;
    scdf[base+2] = ebase + l2;
    scdf[base+3] = ebase + l3;
    if (tid == 0) {
        bc[0] = wred[0]+wred[3]+wred[6]+wred[9];
        bc[1] = wred[1]+wred[4]+wred[7]+wred[10];
        bc[2] = wred[2]+wred[5]+wred[8]+wred[11];
    }
    __syncthreads();

    const double A    = bc[0], B1 = bc[1], C = bc[2];
    const double Pt   = scdf[NS];         // total prob mass
    const double ca   = (double)0.6f;     // fp32(TAU)
    const double cb   = (double)0.4f;     // fp32(1-TAU)
    const double cab  = ca + cb;
    const double GA   = (double)0.1f;     // fp32(GAMMA)
    const double GA2  = GA * GA;
    const double EPSd = (double)1e-12f;

    // ---- parallel pass: first k with g(y_k) >= 0 (count(y_k)=k) ----
    // g >= 0  <=>  t*nr >= GA*s1  (nr>0), resolved without div/sqrt.
    int kmin = 0x7fffffff;
    for (int k = tid; k < NS; k += NT) {
        double z  = (double)sy[k];
        double t  = cab * scdf[k] - ca * Pt;
        double s1 = B1 - z * A;
        double qe = C - z * (2.0 * B1 - z * A) + EPSd;   // nr^2
        double lq = t * t * qe, rq = GA2 * s1 * s1;
        bool ge = (t >= 0.0) ? (s1 <= 0.0 || lq >= rq)
                             : (s1 <  0.0 && lq <= rq);
        if (ge) kmin = min(kmin, k);
    }
    for (int off = 32; off > 0; off >>= 1)
        kmin = min(kmin, __shfl_xor(kmin, off));
    if (lane == 0) wredi[wv] = kmin;
    __syncthreads();

    // ---- thread 0: resolve crossing (closed form), replay, Newton, clamp ----
    if (tid == 0) {
        int kstar = min(min(wredi[0], wredi[1]), min(wredi[2], wredi[3]));

        // boundary values g(0), g(1) exactly as the reference evaluates them
        double g0 = -ca * Pt - GA * B1 / sqrt(C + EPSd);                 // count=0
        int c1 = (sy[NS-1] < 1.0f) ? NS : NS - 1;                        // #{y_i < 1}
        double s1b = B1 - A;
        double qe1 = C - (2.0 * B1 - A) + EPSd;
        double g1 = cab * scdf[c1] - ca * Pt - GA * s1b / sqrt(qe1);

        float zf;
        if (g0 >= 0.0)      zf = 0.0f;
        else if (g1 <= 0.0) zf = 1.0f;
        else {
            int kk = kstar;
            float zlF, zrF;
            if (kk >= NS) { kk = NS; zlF = sy[NS-1]; zrF = 1.0f; }
            else {
                zlF = (kk > 0) ? sy[kk-1] : 0.0f;
                zrF = sy[kk];
            }
            double Phat = cab * scdf[kk] - ca * Pt;

            // Fl = smooth g at zlF with count kk; sign via squared compare
            double zl  = (double)zlF;
            double s1l = B1 - zl * A;
            double qel = C - zl * (2.0 * B1 - zl * A) + EPSd;
            double lql = Phat * Phat * qel, rql = GA2 * s1l * s1l;
            bool Flge = (Phat >= 0.0) ? (s1l <= 0.0 || lql >= rql)
                                      : (s1l <  0.0 && lql <= rql);

            bool   jumpc;
            double zeta;
            if (Flge) { jumpc = true; zeta = zl; }          // crossing at grid jump
            else {
                jumpc = false;                              // interior smooth root: closed form
                double E  = (C * A - B1 * B1) + A * EPSd;   // = A*qe - s1^2 (z-independent, >=0)
                double cc = Phat / (GA * sqrt(A));          // |cc|<1 guaranteed by bracketing
                double u  = cc * sqrt(E / fmax(1.0 - cc * cc, 1e-300));
                zeta = (B1 - u) / A;
                zeta = fmin(fmax(zeta, zl), (double)zrF);   // safety clamp into cell
            }

            // exact fp32 replay of the reference's 60 bisection iterations
            float flo = 0.0f, fhi = 1.0f;
            for (int it = 0; it < 60; ++it) {
                float mid = 0.5f * (flo + fhi);
                bool dec = jumpc ? (mid <= zlF) : ((double)mid < zeta); // == [g(mid) < 0]
                if (dec) flo = mid; else fhi = mid;
            }
            float z0 = 0.5f * (flo + fhi);

            // count(z0) = #{ y_i < z0 }
            int cnt = (kk - 1) + ((zlF < z0) ? 1 : 0) + ((zrF < z0) ? 1 : 0);
            if (cnt < 0) cnt = 0;

            // Newton step at z0 (reference: z = z0 - g/max(gp,1e-8)), then clip
            double z0d = (double)z0;
            double s1 = B1 - z0d * A;
            double qe = C - z0d * (2.0 * B1 - z0d * A) + EPSd;
            double nr = sqrt(qe);
            double inv = 1.0 / nr;
            double g  = cab * scdf[cnt] - ca * Pt - GA * s1 * inv;
            double gp = GA * inv * (A - s1 * s1 * (inv * inv));
            double zn = z0d - g / fmax(gp, (double)1e-8f);
            zn = fmin(fmax(zn, 0.0), 1.0);
            zf = (float)zn;
        }
        zf_sh = zf;
    }
    __syncthreads();

    // ---- outputs: z, pinball, e, w_error (fp32, coalesced rows) ----
    const float zf = zf_sh;
    const size_t Bz = (size_t)B;
    const size_t rb = (size_t)row * NS;
    float* outPin = out + Bz + rb;
    float* outE   = out + Bz + Bz * NS + rb;
    float* outW   = out + Bz + 2 * Bz * NS + rb;
    if (tid == 0) out[row] = zf;
    for (int i = tid; i < NS; i += NT) {
        float e  = sy[i] - zf;
        float pb = fmaxf(0.6f * e, -0.4f * e);   // fp32(TAU)=0.6f, fp32(TAU-1)=-0.4f
        outPin[i] = pb;
        outE[i]   = e;
        outW[i]   = sp[i] * e;
    }
}

extern "C" void kernel_launch(void* const* d_in, const int* in_sizes, int n_in,
                              void* d_out, int out_size, void* d_ws, size_t ws_size,
                              hipStream_t stream)
{
    const float* x = (const float*)d_in[0];
    const float* y = (const float*)d_in[1];
    float* out = (float*)d_out;
    const int Ssz = in_sizes[1];          // 1001
    const int B   = in_sizes[0] / Ssz;    // 32768
    newsvendor_kernel<<<B, NT, 0, stream>>>(x, y, out, B);
}

// Round 5
// 532.211 us; speedup vs baseline: 1.1020x; 1.0360x over previous
//
#include <hip/hip_runtime.h>
#include <hip/hip_bf16.h>

// Newsvendor layer: per-row 1-D convex solve + elementwise outputs.
// One block (256 thr) per row. Thread t owns elements [4t,4t+4):
//   pass A: stage coalesced -> LDS; pass B: registers -> moments + local scan;
//   wave shfl reduce/scan; one barrier; pass C: scdf + sign-tests in registers;
//   thread 0: closed-form root + fp32 bisection replay; pass D: outputs.

constexpr int NS = 1001;
constexpr int SP = 1024;
constexpr int NT = 256;
#define SIDX(i) ((i) + ((i) >> 2))   // bank-conflict pad for fp64 scdf (4-way)

__global__ __launch_bounds__(NT) void newsvendor_kernel(
    const float* __restrict__ x,     // [B, NS]
    const float* __restrict__ ysup,  // [NS]
    float* __restrict__ out,         // [B + 3*B*NS]  (z, pinball, e, w_error)
    int B)
{
    __shared__ float  sp[SP];
    __shared__ float  sy[SP];
    __shared__ double scdf[SP + SP/4];   // padded-index exclusive prefix sums
    __shared__ double wred[12];          // per-wave (A,B1,C)
    __shared__ double wtot[4];           // per-wave scan totals
    __shared__ int    wredi[4];          // per-wave kmin
    __shared__ float  zf_sh;

    const int row  = blockIdx.x;
    const int tid  = threadIdx.x;
    const int lane = tid & 63;
    const int wv   = tid >> 6;
    const float* xr = x + (size_t)row * NS;

    // ---- A: stage coalesced (pad p with 0, y with sentinel) ----
    #pragma unroll
    for (int j = 0; j < 4; ++j) {
        int i = tid + j * NT;
        sp[i] = (i < NS) ? xr[i]   : 0.0f;
        sy[i] = (i < NS) ? ysup[i] : 2.0f;
    }
    __syncthreads();

    // ---- B: per-thread moments + local prefix from registers ----
    const int base = tid * 4;
    float4 pf = *reinterpret_cast<const float4*>(&sp[base]);
    float4 yf = *reinterpret_cast<const float4*>(&sy[base]);
    double p0 = pf.x, p1 = pf.y, p2 = pf.z, p3 = pf.w;
    double y0d = yf.x, y1d = yf.y, y2d = yf.z, y3d = yf.w;
    double q0 = p0*p0, q1 = p1*p1, q2 = p2*p2, q3 = p3*p3;
    double a  = ((q0 + q1) + q2) + q3;
    double b1 = ((q0*y0d + q1*y1d) + q2*y2d) + q3*y3d;
    double c2 = ((q0*y0d*y0d + q1*y1d*y1d) + q2*y2d*y2d) + q3*y3d*y3d;
    double l1 = p0, l2 = p0 + p1, l3 = l2 + p2;
    double s  = l3 + p3;

    for (int off = 32; off > 0; off >>= 1) {
        a  += __shfl_xor(a,  off);
        b1 += __shfl_xor(b1, off);
        c2 += __shfl_xor(c2, off);
    }
    if (lane == 0) { wred[wv*3+0] = a; wred[wv*3+1] = b1; wred[wv*3+2] = c2; }

    double inc = s;
    for (int d = 1; d < 64; d <<= 1) {
        double t = __shfl_up(inc, (unsigned)d);
        if (lane >= d) inc += t;
    }
    if (lane == 63) wtot[wv] = inc;
    __syncthreads();

    // ---- C: scdf + sign tests, all from registers ----
    const double w0 = wtot[0], w1 = wtot[1], w2 = wtot[2], w3 = wtot[3];
    const double Pt = ((w0 + w1) + w2) + w3;
    const double A  = wred[0] + wred[3] + wred[6] + wred[9];
    const double B1 = wred[1] + wred[4] + wred[7] + wred[10];
    const double C  = wred[2] + wred[5] + wred[8] + wred[11];
    double woff = (wv > 0 ? w0 : 0.0) + (wv > 1 ? w1 : 0.0) + (wv > 2 ? w2 : 0.0);
    double eb   = woff + (inc - s);      // exclusive base for this thread
    double sc0 = eb, sc1 = eb + l1, sc2 = eb + l2, sc3 = eb + l3;
    scdf[SIDX(base+0)] = sc0;
    scdf[SIDX(base+1)] = sc1;
    scdf[SIDX(base+2)] = sc2;
    scdf[SIDX(base+3)] = sc3;

    const double ca   = (double)0.6f;
    const double cb   = (double)0.4f;
    const double cab  = ca + cb;
    const double GA   = (double)0.1f;
    const double GA2  = GA * GA;
    const double EPSd = (double)1e-12f;

    int kmin = 0x7fffffff;
    {
        double zz[4] = { y0d, y1d, y2d, y3d };
        double cd[4] = { sc0, sc1, sc2, sc3 };
        #pragma unroll
        for (int j = 0; j < 4; ++j) {
            int k = base + j;
            double z  = zz[j];
            double t  = cab * cd[j] - ca * Pt;
            double s1 = B1 - z * A;
            double qe = C - z * (2.0 * B1 - z * A) + EPSd;
            double lq = t * t * qe, rq = GA2 * s1 * s1;
            bool ge = (t >= 0.0) ? (s1 <= 0.0 || lq >= rq)
                                 : (s1 <  0.0 && lq <= rq);
            if (k < NS && ge) kmin = min(kmin, k);
        }
    }
    for (int off = 32; off > 0; off >>= 1)
        kmin = min(kmin, __shfl_xor(kmin, off));
    if (lane == 0) wredi[wv] = kmin;
    __syncthreads();

    // ---- thread 0: closed-form root, fp32 bisection replay, Newton, clamp ----
    if (tid == 0) {
        int kstar = min(min(wredi[0], wredi[1]), min(wredi[2], wredi[3]));

        double g0 = -ca * Pt - GA * B1 / sqrt(C + EPSd);               // count=0
        int c1 = (sy[NS-1] < 1.0f) ? NS : NS - 1;                      // #{y_i < 1}
        double s1b = B1 - A;
        double qe1 = C - (2.0 * B1 - A) + EPSd;
        double g1 = cab * scdf[SIDX(c1)] - ca * Pt - GA * s1b / sqrt(qe1);

        float zf;
        if (g0 >= 0.0)      zf = 0.0f;
        else if (g1 <= 0.0) zf = 1.0f;
        else {
            int kk = kstar;
            float zlF, zrF;
            if (kk >= NS) { kk = NS; zlF = sy[NS-1]; zrF = 1.0f; }
            else {
                zlF = (kk > 0) ? sy[kk-1] : 0.0f;
                zrF = sy[kk];
            }
            double Phat = cab * scdf[SIDX(kk)] - ca * Pt;

            // sign of smooth g at zlF (count kk) via squared compare
            double zl  = (double)zlF;
            double s1l = B1 - zl * A;
            double qel = C - zl * (2.0 * B1 - zl * A) + EPSd;
            double lql = Phat * Phat * qel, rql = GA2 * s1l * s1l;
            bool Flge = (Phat >= 0.0) ? (s1l <= 0.0 || lql >= rql)
                                      : (s1l <  0.0 && lql <= rql);

            bool   jumpc;
            double zeta;
            if (Flge) { jumpc = true; zeta = zl; }          // crossing at grid jump
            else {
                jumpc = false;                              // interior root, closed form
                double E  = (C * A - B1 * B1) + A * EPSd;   // z-independent, >=0
                double cc = Phat / (GA * sqrt(A));
                double u  = cc * sqrt(E / fmax(1.0 - cc * cc, 1e-300));
                zeta = (B1 - u) / A;
                zeta = fmin(fmax(zeta, zl), (double)zrF);
            }

            // exact fp32 replay of the 60 bisection iterations (early fixed point)
            float flo = 0.0f, fhi = 1.0f;
            for (int it = 0; it < 60; ++it) {
                float mid = 0.5f * (flo + fhi);
                bool dec = jumpc ? (mid <= zlF) : ((double)mid < zeta);
                bool fixedpt = (mid == flo) || (mid == fhi);
                if (dec) flo = mid; else fhi = mid;
                if (fixedpt) break;
            }
            float z0 = 0.5f * (flo + fhi);

            int cnt = (kk - 1) + ((zlF < z0) ? 1 : 0) + ((zrF < z0) ? 1 : 0);
            if (cnt < 0) cnt = 0;

            double z0d = (double)z0;
            double s1 = B1 - z0d * A;
            double qe = C - z0d * (2.0 * B1 - z0d * A) + EPSd;
            double nr = sqrt(qe);
            double invn = 1.0 / nr;
            double g  = cab * scdf[SIDX(cnt)] - ca * Pt - GA * s1 * invn;
            double gp = GA * invn * (A - s1 * s1 * (invn * invn));
            double zn = z0d - g / fmax(gp, (double)1e-8f);
            zn = fmin(fmax(zn, 0.0), 1.0);
            zf = (float)zn;
        }
        zf_sh = zf;
    }
    __syncthreads();

    // ---- D: outputs (coalesced scalar, nontemporal) ----
    const float zf = zf_sh;
    const size_t Bz = (size_t)B;
    const size_t rb = (size_t)row * NS;
    float* outPin = out + Bz + rb;
    float* outE   = out + Bz + Bz * NS + rb;
    float* outW   = out + Bz + 2 * Bz * NS + rb;
    if (tid == 0) out[row] = zf;
    #pragma unroll
    for (int j = 0; j < 4; ++j) {
        int i = tid + j * NT;
        if (i < NS) {
            float e  = sy[i] - zf;
            float pb = fmaxf(0.6f * e, -0.4f * e);
            __builtin_nontemporal_store(pb,        &outPin[i]);
            __builtin_nontemporal_store(e,         &outE[i]);
            __builtin_nontemporal_store(sp[i] * e, &outW[i]);
        }
    }
}

extern "C" void kernel_launch(void* const* d_in, const int* in_sizes, int n_in,
                              void* d_out, int out_size, void* d_ws, size_t ws_size,
                              hipStream_t stream)
{
    const float* x = (const float*)d_in[0];
    const float* y = (const float*)d_in[1];
    float* out = (float*)d_out;
    const int Ssz = in_sizes[1];          // 1001
    const int B   = in_sizes[0] / Ssz;    // 32768
    newsvendor_kernel<<<B, NT, 0, stream>>>(x, y, out, B);
}